// Round 4
// baseline (178.024 us; speedup 1.0000x reference)
//
#include <hip/hip_runtime.h>

#define N_NODES 100000
#define N_EDGES 1250000
#define IN_CH 128
#define OUT_CH 64

#define NPB 128           // nodes per bin; bin = row >> 7
#define ACCS2 33          // u64 acc row stride (pad): 128*33*8 = 33792 B LDS
#define NBINS 782         // ceil(100000/128)
#define LSTRIDE 783       // lscan2d row stride (NBINS+1 entries per sort block)
#define RECCAP 2048       // LDS record cap per bin in gather (mean 1598, +11 sigma)
#define NB1 256           // sort blocks
#define B1T 512
#define CH1 ((N_EDGES + NB1 - 1) / NB1)   // 4883 edges per sort block
#define MAXU ((CH1 + B1T - 1) / B1T)      // 10 edges cached per thread
#define GEMM_BLOCKS ((N_NODES + 127) / 128)  // 782 gemm blocks @ 128 nodes

// fixed-point: q = rn(val * sc), biased by 2^23 per contribution (sign-safe,
// ulp(2^23)=1.0; lo-half total stays << 2^32 at max ~45 edges/row)
#define QSCALE 8192.0f
#define QBIAS_F 8388608.0f
#define QBIAS_U 8388608u
#define INV_QSCALE 1.220703125e-4f   // 2^-13
#define SCALE_DEG 33554432.0f        // 2^25 fixed-point for degree accum
#define INV_SCALE_DEG 2.9802322387695312e-08f

typedef __attribute__((ext_vector_type(8))) short short8;
typedef __attribute__((ext_vector_type(4))) float f32x4;

// round-to-nearest-even f32 -> bf16
__device__ inline unsigned int f2bf(float f) {
    unsigned int u = __float_as_uint(f);
    unsigned int r = ((u >> 16) & 1u) + 0x7FFFu;
    return (u + r) >> 16;
}
__device__ inline float bf_lo(unsigned int p) { return __uint_as_float(p << 16); }
__device__ inline float bf_hi(unsigned int p) { return __uint_as_float(p & 0xFFFF0000u); }

// biased fixed-point quantize of one packed bf16x2, scaled by sc = QSCALE*dis_col
__device__ inline unsigned long long qpacks(unsigned int p, float sc) {
    unsigned int lo = (unsigned int)__float2int_rn(fmaf(bf_lo(p), sc, QBIAS_F));
    unsigned int hi = (unsigned int)__float2int_rn(fmaf(bf_hi(p), sc, QBIAS_F));
    return ((unsigned long long)hi << 32) | (unsigned long long)lo;
}

// ---------------------------------------------------------------------------
// Init: W[128,64] fp32 -> Wb bf16 in MFMA A-fragment layout. 1024 threads.
// ---------------------------------------------------------------------------
__global__ __launch_bounds__(256) void init_kernel(const float* __restrict__ W,
                                                   unsigned int* __restrict__ Wb) {
    int g = blockIdx.x * 256 + threadIdx.x;   // 1024 lane-slots
    int c = g >> 8;
    int t4 = (g >> 6) & 3;
    int l = g & 63;
    int q = l >> 4, r15 = l & 15;
    unsigned int o[4];
#pragma unroll
    for (int jj = 0; jj < 4; ++jj) {
        float f0 = W[(c * 32 + q * 8 + 2 * jj)     * OUT_CH + t4 * 16 + r15];
        float f1 = W[(c * 32 + q * 8 + 2 * jj + 1) * OUT_CH + t4 * 16 + r15];
        o[jj] = f2bf(f0) | (f2bf(f1) << 16);
    }
    *(uint4*)(Wb + (size_t)g * 4) = make_uint4(o[0], o[1], o[2], o[3]);
}

// ---------------------------------------------------------------------------
// Fused heterogeneous dispatch:
//   blocks [0, NB1)            : LDS counting sort of this block's edge chunk
//                                by bin (row>>7). ALL global writes coalesced:
//                                sorted run -> brec[k*CH1..], local scan row
//                                -> lscan2d[k][*]. Zero global atomics, zero
//                                scattered stores (rounds 0-3 post-mortem:
//                                1.25M scattered 8B brec stores were the
//                                ~25us structural tail in every variant).
//   blocks [NB1, NB1+GEMM_BLKS): bf16-MFMA GEMM hs = bf16(x @ W), UNSCALED
// ---------------------------------------------------------------------------
__global__ __launch_bounds__(512) void fused_kernel(const float* __restrict__ x,
                                                    const unsigned int* __restrict__ Wb,
                                                    const int* __restrict__ ei,
                                                    const float* __restrict__ ew,
                                                    int* __restrict__ lscan2d,
                                                    int2* __restrict__ brec,
                                                    unsigned int* __restrict__ hs) {
    __shared__ int2 srec[CH1];        // 39064 B sorted run
    __shared__ int shist[NBINS];      // hist, then reused as rank counters
    __shared__ int sscan[NBINS + 2];  // exclusive scan (incl. total at [NBINS])
    __shared__ int ssum[256];         // chunk sums for scan
    const int tid = threadIdx.x;

    if (blockIdx.x < NB1) {
        // ----- sort half -----
        for (int i = tid; i < NBINS; i += B1T) shist[i] = 0;
        __syncthreads();

        const int e0 = blockIdx.x * CH1;
        const int total = (e0 + CH1 < N_EDGES) ? CH1 : N_EDGES - e0;

        int rowv[MAXU], colv[MAXU];
        float wv[MAXU];
#pragma unroll
        for (int u = 0; u < MAXU; ++u) {
            int e = e0 + tid + u * B1T;
            bool ok = (tid + u * B1T) < total;
            rowv[u] = ok ? ei[e] : -1;
            colv[u] = ok ? ei[N_EDGES + e] : 0;
            wv[u]   = ok ? ew[e] : 0.0f;
            if (ok) atomicAdd(&shist[rowv[u] >> 7], 1);
        }
        __syncthreads();

        // block-local exclusive scan: shist[0..NBINS) -> sscan[0..NBINS]
        int a0 = 0, a1 = 0, a2 = 0, a3 = 0, part = 0;
        const int b0 = tid * 4;
        if (tid < 256) {
            a0 = (b0 + 0 < NBINS) ? shist[b0 + 0] : 0;
            a1 = (b0 + 1 < NBINS) ? shist[b0 + 1] : 0;
            a2 = (b0 + 2 < NBINS) ? shist[b0 + 2] : 0;
            a3 = (b0 + 3 < NBINS) ? shist[b0 + 3] : 0;
            part = a0 + a1 + a2 + a3;
            ssum[tid] = part;
        }
        __syncthreads();
#pragma unroll
        for (int d = 1; d < 256; d <<= 1) {
            int add = 0;
            if (tid >= d && tid < 256) add = ssum[tid - d];
            __syncthreads();
            if (tid < 256) ssum[tid] += add;
            __syncthreads();
        }
        if (tid < 256) {
            int base = ssum[tid] - part;   // exclusive chunk base
            if (b0 + 0 <= NBINS) sscan[b0 + 0] = base;
            if (b0 + 1 <= NBINS) sscan[b0 + 1] = base + a0;
            if (b0 + 2 <= NBINS) sscan[b0 + 2] = base + a0 + a1;
            if (b0 + 3 <= NBINS) sscan[b0 + 3] = base + a0 + a1 + a2;
        }
        __syncthreads();

        // reuse shist as rank counters
        for (int i = tid; i < NBINS; i += B1T) shist[i] = 0;
        __syncthreads();

        // scatter registers -> LDS sorted buffer (exact slots, memory-safe by
        // construction: sscan[bb]+rk < total <= CH1)
#pragma unroll
        for (int u = 0; u < MAXU; ++u) {
            if (rowv[u] >= 0) {
                int bb = rowv[u] >> 7;
                int rk = atomicAdd(&shist[bb], 1);
                srec[sscan[bb] + rk] = make_int2(((rowv[u] & 127) << 17) | colv[u],
                                                 __float_as_int(wv[u]));
            }
        }
        __syncthreads();

        // coalesced streaming writeout
        for (int i = tid; i < total; i += B1T) brec[e0 + i] = srec[i];
        int* lrow = lscan2d + blockIdx.x * LSTRIDE;
        for (int i = tid; i <= NBINS; i += B1T) lrow[i] = sscan[i];
    } else {
        // ----- GEMM half: 128 nodes per block, 8 waves x 16 rows -----
        const int blk  = blockIdx.x - NB1;
        const int w    = tid >> 6;
        const int lane = tid & 63;
        const int q    = lane >> 4, r15 = lane & 15;
        const int node = blk * 128 + w * 16 + r15;
        const int nl   = (node < N_NODES) ? node : N_NODES - 1;   // clamp loads
        const float* xrow = x + (size_t)nl * IN_CH;

        f32x4 acc[4];
#pragma unroll
        for (int t = 0; t < 4; ++t) acc[t] = (f32x4){0.f, 0.f, 0.f, 0.f};

#pragma unroll
        for (int c = 0; c < 4; ++c) {
            float4 xa = *(const float4*)(xrow + c * 32 + q * 8);
            float4 xb = *(const float4*)(xrow + c * 32 + q * 8 + 4);
            short8 bfrag;
            bfrag[0] = (short)f2bf(xa.x); bfrag[1] = (short)f2bf(xa.y);
            bfrag[2] = (short)f2bf(xa.z); bfrag[3] = (short)f2bf(xa.w);
            bfrag[4] = (short)f2bf(xb.x); bfrag[5] = (short)f2bf(xb.y);
            bfrag[6] = (short)f2bf(xb.z); bfrag[7] = (short)f2bf(xb.w);
#pragma unroll
            for (int t = 0; t < 4; ++t) {
                short8 afrag = *(const short8*)(Wb + (size_t)((c * 4 + t) * 64 + lane) * 4);
                acc[t] = __builtin_amdgcn_mfma_f32_16x16x32_bf16(afrag, bfrag, acc[t], 0, 0, 0);
            }
        }

        if (node < N_NODES) {
#pragma unroll
            for (int t = 0; t < 4; ++t) {
                unsigned int p0 = f2bf(acc[t][0]) | (f2bf(acc[t][1]) << 16);
                unsigned int p1 = f2bf(acc[t][2]) | (f2bf(acc[t][3]) << 16);
                *(uint2*)(hs + (size_t)node * 32 + t * 8 + q * 2) = make_uint2(p0, p1);
            }
        }
    }
}

// ---------------------------------------------------------------------------
// Degree pass: one 256-thread block per bin. Thread t walks sort-block t's
// contiguous segment for this bin; INT fixed-point LDS deg accumulate -> dis.
// ---------------------------------------------------------------------------
__global__ __launch_bounds__(256) void bin2_kernel(const int* __restrict__ lscan2d,
                                                   const int2* __restrict__ brec,
                                                   float* __restrict__ dis_g) {
    __shared__ int deg[NPB];
    const int t = threadIdx.x;
    const int b = blockIdx.x;
    if (t < NPB) deg[t] = 0;
    __syncthreads();

    int st = lscan2d[t * LSTRIDE + b];
    int en = lscan2d[t * LSTRIDE + b + 1];
    const int2* seg = brec + (size_t)t * CH1;
    for (int j = st; j < en; ++j) {
        int2 rec = seg[j];
        atomicAdd(&deg[rec.x >> 17], __float2int_rn(__int_as_float(rec.y) * SCALE_DEG));
    }
    __syncthreads();

    int node = b * NPB + t;
    if (t < NPB && node < N_NODES) {
        float d = (float)deg[t] * INV_SCALE_DEG;
        dis_g[node] = (d == 0.0f) ? 0.0f : (1.0f / sqrtf(d));
    }
}

// ---------------------------------------------------------------------------
// Bin-gather: one 512-thread block per 128-node bin. Phase 0 compacts the
// bin's 256 contiguous segments into LDS (4B records - gather never needs the
// weight). Main loop: u64-packed LDS atomics (2 biased fixed-point channels
// per ds_add_u64), 4-deep edge pipeline against the L2/L3 hs gather.
// ---------------------------------------------------------------------------
__global__ __launch_bounds__(512) void gather_kernel(const int* __restrict__ lscan2d,
                                                     const int2* __restrict__ brec,
                                                     const uint4* __restrict__ hs, // 8/row
                                                     const float* __restrict__ dis,
                                                     const float* __restrict__ b,
                                                     float* __restrict__ out) {
    __shared__ unsigned long long acc[NPB * ACCS2];   // 33792 B
    __shared__ int cnt[NPB];
    __shared__ int recs[RECCAP];                      // 8192 B compacted records
    __shared__ int segoff[256];                       // inclusive scan of seg lens
    __shared__ int mtot_s;
    const int tid = threadIdx.x;
    const int blk = blockIdx.x;
    for (int k = tid; k < NPB * ACCS2; k += 512) acc[k] = 0ull;
    if (tid < NPB) cnt[tid] = 0;

    // segment lengths
    int st = 0, len = 0;
    if (tid < 256) {
        st  = lscan2d[tid * LSTRIDE + blk];
        len = lscan2d[tid * LSTRIDE + blk + 1] - st;
        segoff[tid] = len;
    }
    __syncthreads();
    // inclusive Hillis-Steele scan over segoff[0..255]
#pragma unroll
    for (int d = 1; d < 256; d <<= 1) {
        int add = 0;
        if (tid >= d && tid < 256) add = segoff[tid - d];
        __syncthreads();
        if (tid < 256) segoff[tid] += add;
        __syncthreads();
    }
    if (tid == 255) mtot_s = segoff[255];
    __syncthreads();
    int m = mtot_s;
    if (m > RECCAP) m = RECCAP;

    // compact: thread t copies its segment (contiguous global reads)
    if (tid < 256) {
        int off = segoff[tid] - len;   // exclusive base
        const int2* seg = brec + (size_t)tid * CH1 + st;
        for (int i = 0; i < len; ++i) {
            int p = off + i;
            if (p < RECCAP) recs[p] = seg[i].x;
        }
    }
    __syncthreads();

    const int wid = tid >> 6, lane = tid & 63;
    const int sub = lane >> 3, l8 = lane & 7;

    for (int j0 = wid * 32; j0 < m; j0 += 256) {
        bool ok[4];
        int rec[4];
        uint4 p[4];
        float sc[4];
#pragma unroll
        for (int s = 0; s < 4; ++s) {
            int jj = j0 + 8 * s + sub;
            ok[s] = jj < m;
            rec[s] = ok[s] ? recs[jj] : 0;
        }
#pragma unroll
        for (int s = 0; s < 4; ++s) {
            p[s] = ok[s] ? hs[(size_t)(rec[s] & 0x1FFFF) * 8 + l8]
                         : make_uint4(0, 0, 0, 0);
            sc[s] = ok[s] ? QSCALE * dis[rec[s] & 0x1FFFF] : 0.0f;
        }
#pragma unroll
        for (int s = 0; s < 4; ++s) {
            if (ok[s]) {
                int ba = (rec[s] >> 17) * ACCS2 + 4 * l8;
                atomicAdd(&acc[ba + 0], qpacks(p[s].x, sc[s]));
                atomicAdd(&acc[ba + 1], qpacks(p[s].y, sc[s]));
                atomicAdd(&acc[ba + 2], qpacks(p[s].z, sc[s]));
                atomicAdd(&acc[ba + 3], qpacks(p[s].w, sc[s]));
                if (l8 == 0) atomicAdd(&cnt[rec[s] >> 17], 1);
            }
        }
    }
    __syncthreads();

    // writeout: wave w handles node-locals [w*16, w*16+16); lane = channel c.
    // channel c lives in 32-bit half (c&1) of u64 slot (c>>1).
    const unsigned int* acc32 = (const unsigned int*)acc;
    float bc = b[lane];
    int half = lane & 1, slot = lane >> 1;
#pragma unroll 4
    for (int r = 0; r < 16; ++r) {
        int nl = wid * 16 + r;
        int node = blk * NPB + nl;
        if (node < N_NODES) {
            unsigned int raw = acc32[(nl * ACCS2 + slot) * 2 + half];
            int qsum = (int)(raw - (unsigned int)cnt[nl] * QBIAS_U);
            float di = dis[node] * INV_QSCALE;
            out[(size_t)node * OUT_CH + lane] = (float)qsum * di + bc;
        }
    }
}

extern "C" void kernel_launch(void* const* d_in, const int* in_sizes, int n_in,
                              void* d_out, int out_size, void* d_ws, size_t ws_size,
                              hipStream_t stream) {
    const float* x  = (const float*)d_in[0];
    const int*   ei = (const int*)d_in[1];
    const float* ew = (const float*)d_in[2];
    const float* W  = (const float*)d_in[3];
    const float* b  = (const float*)d_in[4];
    float* out = (float*)d_out;

    // Workspace layout (4-byte units)
    unsigned int* hs = (unsigned int*)d_ws;                   // N*32 uints (12.8 MB)
    unsigned int* Wb = hs + (size_t)N_NODES * 32;             // 4096 uints
    int* lscan2d = (int*)(Wb + 4096);                         // NB1*LSTRIDE ints
    float* dis   = (float*)(lscan2d + NB1 * LSTRIDE);         // N floats
    int2* brec   = (int2*)(dis + N_NODES);                    // NB1*CH1 int2 (10 MB)
    (void)ws_size; (void)in_sizes; (void)n_in; (void)out_size;

    init_kernel<<<4, 256, 0, stream>>>(W, Wb);
    fused_kernel<<<NB1 + GEMM_BLOCKS, 512, 0, stream>>>(x, Wb, ei, ew,
                                                        lscan2d, brec, hs);
    bin2_kernel<<<NBINS, 256, 0, stream>>>(lscan2d, brec, dis);
    gather_kernel<<<NBINS, 512, 0, stream>>>(lscan2d, brec, (const uint4*)hs,
                                             dis, b, out);
}

// Round 5
// 159.737 us; speedup vs baseline: 1.1145x; 1.1145x over previous
//
#include <hip/hip_runtime.h>

#define N_NODES 100000
#define N_EDGES 1250000
#define IN_CH 128
#define OUT_CH 64

#define NPB 128           // nodes per bin; bin = row >> 7
#define ACCS2 33          // u64 acc row stride (pad): 128*33*8 = 33792 B LDS
#define NBINS 782         // ceil(100000/128)
#define LSTRIDE 783       // lscan2d row stride (NBINS+1 entries per sort block)
#define RECCAP 2048       // bin arena cap (mean 1598, sigma ~40, +11 sigma)
#define NB1 384           // sort blocks (srec 26KB -> 4 blocks/CU in fused)
#define B1T 512
#define BPT 384           // binprep threads (1 per sort-block segment)
#define CH1 ((N_EDGES + NB1 - 1) / NB1)   // 3256 edges per sort block
#define MAXU ((CH1 + B1T - 1) / B1T)      // 7 edges cached per thread
#define GEMM_BLOCKS ((N_NODES + 127) / 128)  // 782 gemm blocks @ 128 nodes

// fixed-point: q = rn(val * sc), biased by 2^23 per contribution (sign-safe,
// ulp(2^23)=1.0; lo-half total stays << 2^32 at max ~45 edges/row)
#define QSCALE 8192.0f
#define QBIAS_F 8388608.0f
#define QBIAS_U 8388608u
#define INV_QSCALE 1.220703125e-4f   // 2^-13
#define SCALE_DEG 33554432.0f        // 2^25 fixed-point for degree accum
#define INV_SCALE_DEG 2.9802322387695312e-08f

typedef __attribute__((ext_vector_type(8))) short short8;
typedef __attribute__((ext_vector_type(4))) float f32x4;

// round-to-nearest-even f32 -> bf16
__device__ inline unsigned int f2bf(float f) {
    unsigned int u = __float_as_uint(f);
    unsigned int r = ((u >> 16) & 1u) + 0x7FFFu;
    return (u + r) >> 16;
}
__device__ inline float bf_lo(unsigned int p) { return __uint_as_float(p << 16); }
__device__ inline float bf_hi(unsigned int p) { return __uint_as_float(p & 0xFFFF0000u); }

// biased fixed-point quantize of one packed bf16x2, scaled by sc = QSCALE*dis_col
__device__ inline unsigned long long qpacks(unsigned int p, float sc) {
    unsigned int lo = (unsigned int)__float2int_rn(fmaf(bf_lo(p), sc, QBIAS_F));
    unsigned int hi = (unsigned int)__float2int_rn(fmaf(bf_hi(p), sc, QBIAS_F));
    return ((unsigned long long)hi << 32) | (unsigned long long)lo;
}

// ---------------------------------------------------------------------------
// Init: W[128,64] fp32 -> Wb bf16 in MFMA A-fragment layout. 1024 threads.
// ---------------------------------------------------------------------------
__global__ __launch_bounds__(256) void init_kernel(const float* __restrict__ W,
                                                   unsigned int* __restrict__ Wb) {
    int g = blockIdx.x * 256 + threadIdx.x;   // 1024 lane-slots
    int c = g >> 8;
    int t4 = (g >> 6) & 3;
    int l = g & 63;
    int q = l >> 4, r15 = l & 15;
    unsigned int o[4];
#pragma unroll
    for (int jj = 0; jj < 4; ++jj) {
        float f0 = W[(c * 32 + q * 8 + 2 * jj)     * OUT_CH + t4 * 16 + r15];
        float f1 = W[(c * 32 + q * 8 + 2 * jj + 1) * OUT_CH + t4 * 16 + r15];
        o[jj] = f2bf(f0) | (f2bf(f1) << 16);
    }
    *(uint4*)(Wb + (size_t)g * 4) = make_uint4(o[0], o[1], o[2], o[3]);
}

// ---------------------------------------------------------------------------
// Fused heterogeneous dispatch:
//   blocks [0, NB1)            : LDS counting sort of this block's edge chunk
//                                by bin (row>>7). ALL global writes coalesced
//                                (sorted run -> brec[k*CH1..], scan row ->
//                                lscan2d[k][*]). Zero global atomics / zero
//                                scattered stores (R0-R3 lesson). NB1=384 so
//                                LDS = 33.3 KB -> 4 blocks/CU (R4 was 3).
//   blocks [NB1, NB1+GEMM_BLKS): bf16-MFMA GEMM hs = bf16(x @ W), UNSCALED
// ---------------------------------------------------------------------------
__global__ __launch_bounds__(512) void fused_kernel(const float* __restrict__ x,
                                                    const unsigned int* __restrict__ Wb,
                                                    const int* __restrict__ ei,
                                                    const float* __restrict__ ew,
                                                    int* __restrict__ lscan2d,
                                                    int2* __restrict__ brec,
                                                    unsigned int* __restrict__ hs) {
    __shared__ int2 srec[CH1];        // 26048 B sorted run
    __shared__ int shist[NBINS];      // hist, then reused as rank counters
    __shared__ int sscan[NBINS + 2];  // exclusive scan (incl. total at [NBINS])
    __shared__ int ssum[256];         // chunk sums for scan
    const int tid = threadIdx.x;

    if (blockIdx.x < NB1) {
        // ----- sort half -----
        for (int i = tid; i < NBINS; i += B1T) shist[i] = 0;
        __syncthreads();

        const int e0 = blockIdx.x * CH1;
        const int total = (e0 + CH1 < N_EDGES) ? CH1 : N_EDGES - e0;

        int rowv[MAXU], colv[MAXU];
        float wv[MAXU];
#pragma unroll
        for (int u = 0; u < MAXU; ++u) {
            int e = e0 + tid + u * B1T;
            bool ok = (tid + u * B1T) < total;
            rowv[u] = ok ? ei[e] : -1;
            colv[u] = ok ? ei[N_EDGES + e] : 0;
            wv[u]   = ok ? ew[e] : 0.0f;
            if (ok) atomicAdd(&shist[rowv[u] >> 7], 1);
        }
        __syncthreads();

        // block-local exclusive scan: shist[0..NBINS) -> sscan[0..NBINS]
        int a0 = 0, a1 = 0, a2 = 0, a3 = 0, part = 0;
        const int b0 = tid * 4;
        if (tid < 256) {
            a0 = (b0 + 0 < NBINS) ? shist[b0 + 0] : 0;
            a1 = (b0 + 1 < NBINS) ? shist[b0 + 1] : 0;
            a2 = (b0 + 2 < NBINS) ? shist[b0 + 2] : 0;
            a3 = (b0 + 3 < NBINS) ? shist[b0 + 3] : 0;
            part = a0 + a1 + a2 + a3;
            ssum[tid] = part;
        }
        __syncthreads();
#pragma unroll
        for (int d = 1; d < 256; d <<= 1) {
            int add = 0;
            if (tid >= d && tid < 256) add = ssum[tid - d];
            __syncthreads();
            if (tid < 256) ssum[tid] += add;
            __syncthreads();
        }
        if (tid < 256) {
            int base = ssum[tid] - part;   // exclusive chunk base
            if (b0 + 0 <= NBINS) sscan[b0 + 0] = base;
            if (b0 + 1 <= NBINS) sscan[b0 + 1] = base + a0;
            if (b0 + 2 <= NBINS) sscan[b0 + 2] = base + a0 + a1;
            if (b0 + 3 <= NBINS) sscan[b0 + 3] = base + a0 + a1 + a2;
        }
        __syncthreads();

        // reuse shist as rank counters
        for (int i = tid; i < NBINS; i += B1T) shist[i] = 0;
        __syncthreads();

        // scatter registers -> LDS sorted buffer (exact slots, memory-safe by
        // construction: sscan[bb]+rk < total <= CH1)
#pragma unroll
        for (int u = 0; u < MAXU; ++u) {
            if (rowv[u] >= 0) {
                int bb = rowv[u] >> 7;
                int rk = atomicAdd(&shist[bb], 1);
                srec[sscan[bb] + rk] = make_int2(((rowv[u] & 127) << 17) | colv[u],
                                                 __float_as_int(wv[u]));
            }
        }
        __syncthreads();

        // coalesced streaming writeout
        for (int i = tid; i < total; i += B1T) brec[e0 + i] = srec[i];
        int* lrow = lscan2d + blockIdx.x * LSTRIDE;
        for (int i = tid; i <= NBINS; i += B1T) lrow[i] = sscan[i];
    } else {
        // ----- GEMM half: 128 nodes per block, 8 waves x 16 rows -----
        const int blk  = blockIdx.x - NB1;
        const int w    = tid >> 6;
        const int lane = tid & 63;
        const int q    = lane >> 4, r15 = lane & 15;
        const int node = blk * 128 + w * 16 + r15;
        const int nl   = (node < N_NODES) ? node : N_NODES - 1;   // clamp loads
        const float* xrow = x + (size_t)nl * IN_CH;

        f32x4 acc[4];
#pragma unroll
        for (int t = 0; t < 4; ++t) acc[t] = (f32x4){0.f, 0.f, 0.f, 0.f};

#pragma unroll
        for (int c = 0; c < 4; ++c) {
            float4 xa = *(const float4*)(xrow + c * 32 + q * 8);
            float4 xb = *(const float4*)(xrow + c * 32 + q * 8 + 4);
            short8 bfrag;
            bfrag[0] = (short)f2bf(xa.x); bfrag[1] = (short)f2bf(xa.y);
            bfrag[2] = (short)f2bf(xa.z); bfrag[3] = (short)f2bf(xa.w);
            bfrag[4] = (short)f2bf(xb.x); bfrag[5] = (short)f2bf(xb.y);
            bfrag[6] = (short)f2bf(xb.z); bfrag[7] = (short)f2bf(xb.w);
#pragma unroll
            for (int t = 0; t < 4; ++t) {
                short8 afrag = *(const short8*)(Wb + (size_t)((c * 4 + t) * 64 + lane) * 4);
                acc[t] = __builtin_amdgcn_mfma_f32_16x16x32_bf16(afrag, bfrag, acc[t], 0, 0, 0);
            }
        }

        if (node < N_NODES) {
#pragma unroll
            for (int t = 0; t < 4; ++t) {
                unsigned int p0 = f2bf(acc[t][0]) | (f2bf(acc[t][1]) << 16);
                unsigned int p1 = f2bf(acc[t][2]) | (f2bf(acc[t][3]) << 16);
                *(uint2*)(hs + (size_t)node * 32 + t * 8 + q * 2) = make_uint2(p0, p1);
            }
        }
    }
}

// ---------------------------------------------------------------------------
// Binprep: one 384-thread block per bin. Concatenates the bin's 384 sorted
// segments into a bin-contiguous 4B record arena (brec2) via load-balanced
// binary-search copy (consecutive output slots -> near-coalesced reads;
// fixes R4's serial per-thread compaction that inflated FETCH 6x). Fused
// degree pass: ONE packed u64 LDS atomic per record accumulates weighted
// deg (lo 32b fixed-point) + edge count (hi 32b). Emits dis[], qcnt[], mtot.
// Small LDS (12.3 KB) -> high occupancy, latency well hidden.
// ---------------------------------------------------------------------------
__global__ __launch_bounds__(BPT) void binprep_kernel(const int* __restrict__ lscan2d,
                                                      const int2* __restrict__ brec,
                                                      int* __restrict__ brec2,
                                                      float* __restrict__ dis,
                                                      int* __restrict__ qcnt,
                                                      int* __restrict__ mtot) {
    __shared__ int sst[NB1];
    __shared__ int segoff[NB1];       // inclusive scan of segment lengths
    __shared__ int recs[RECCAP];      // 8192 B compacted 4B records
    __shared__ unsigned long long degcnt[NPB];  // lo: fixed-point wdeg, hi: count
    const int t = threadIdx.x;
    const int b = blockIdx.x;

    if (t < NPB) degcnt[t] = 0ull;
    {
        int st  = lscan2d[t * LSTRIDE + b];
        int en  = lscan2d[t * LSTRIDE + b + 1];
        sst[t] = st;
        segoff[t] = en - st;
    }
    __syncthreads();
#pragma unroll
    for (int d = 1; d < NB1; d <<= 1) {   // Hillis-Steele inclusive scan (384)
        int add = (t >= d) ? segoff[t - d] : 0;
        __syncthreads();
        segoff[t] += add;
        __syncthreads();
    }
    const int m = segoff[NB1 - 1];

    for (int p = t; p < m; p += BPT) {
        // smallest k with segoff[k] > p
        int lo = 0, hi = NB1 - 1;
        while (lo < hi) {
            int mid = (lo + hi) >> 1;
            if (segoff[mid] > p) hi = mid; else lo = mid + 1;
        }
        int excl = (lo == 0) ? 0 : segoff[lo - 1];
        int2 rec = brec[(size_t)lo * CH1 + sst[lo] + (p - excl)];
        if (p < RECCAP) recs[p] = rec.x;
        unsigned int qd = (unsigned int)__float2int_rn(__int_as_float(rec.y) * SCALE_DEG);
        atomicAdd(&degcnt[rec.x >> 17],
                  (1ull << 32) | (unsigned long long)qd);
    }
    __syncthreads();

    if (t < NPB) {
        int node = b * NPB + t;
        if (node < N_NODES) {
            unsigned long long dc = degcnt[t];
            float d = (float)(unsigned int)dc * INV_SCALE_DEG;
            dis[node]  = (d == 0.0f) ? 0.0f : (1.0f / sqrtf(d));
            qcnt[node] = (int)(dc >> 32);
        }
    }
    int mc = (m < RECCAP) ? m : RECCAP;
    if (t == 0) mtot[b] = mc;
    for (int p = t; p < mc; p += BPT)   // coalesced streaming writeout
        brec2[(size_t)b * RECCAP + p] = recs[p];
}

// ---------------------------------------------------------------------------
// Bin-gather: one 512-thread block per 128-node bin. Lean again (R4 lesson:
// no preamble, no cnt atomics; LDS 33.8 KB -> 4 blocks/CU). 4B bin-contiguous
// records; u64-packed LDS atomics (2 biased fixed-point channels per
// ds_add_u64); 4-deep edge pipeline against the L3-latency-bound hs gather.
// ---------------------------------------------------------------------------
__global__ __launch_bounds__(512) void gather_kernel(const int* __restrict__ mtot,
                                                     const int* __restrict__ brec2,
                                                     const uint4* __restrict__ hs, // 8/row
                                                     const float* __restrict__ dis,
                                                     const int* __restrict__ qcnt,
                                                     const float* __restrict__ b,
                                                     float* __restrict__ out) {
    __shared__ unsigned long long acc[NPB * ACCS2];   // 33792 B
    const int tid = threadIdx.x;
    const int blk = blockIdx.x;
    for (int k = tid; k < NPB * ACCS2; k += 512) acc[k] = 0ull;
    __syncthreads();

    const int m = mtot[blk];
    const int rbase = blk * RECCAP;

    const int wid = tid >> 6, lane = tid & 63;
    const int sub = lane >> 3, l8 = lane & 7;

    for (int j0 = wid * 32; j0 < m; j0 += 256) {
        bool ok[4];
        int rec[4];
        uint4 p[4];
        float sc[4];
#pragma unroll
        for (int s = 0; s < 4; ++s) {
            int jj = j0 + 8 * s + sub;
            ok[s] = jj < m;
            rec[s] = ok[s] ? brec2[rbase + jj] : 0;
        }
#pragma unroll
        for (int s = 0; s < 4; ++s) {
            p[s] = ok[s] ? hs[(size_t)(rec[s] & 0x1FFFF) * 8 + l8]
                         : make_uint4(0, 0, 0, 0);
            sc[s] = ok[s] ? QSCALE * dis[rec[s] & 0x1FFFF] : 0.0f;
        }
#pragma unroll
        for (int s = 0; s < 4; ++s) {
            if (ok[s]) {
                int ba = (rec[s] >> 17) * ACCS2 + 4 * l8;
                atomicAdd(&acc[ba + 0], qpacks(p[s].x, sc[s]));
                atomicAdd(&acc[ba + 1], qpacks(p[s].y, sc[s]));
                atomicAdd(&acc[ba + 2], qpacks(p[s].z, sc[s]));
                atomicAdd(&acc[ba + 3], qpacks(p[s].w, sc[s]));
            }
        }
    }
    __syncthreads();

    // writeout: wave w handles node-locals [w*16, w*16+16); lane = channel c.
    // channel c lives in 32-bit half (c&1) of u64 slot (c>>1). Bias removal
    // uses the precomputed per-node edge count qcnt (binprep).
    const unsigned int* acc32 = (const unsigned int*)acc;
    float bc = b[lane];
    int half = lane & 1, slot = lane >> 1;
#pragma unroll 4
    for (int r = 0; r < 16; ++r) {
        int nl = wid * 16 + r;
        int node = blk * NPB + nl;
        if (node < N_NODES) {
            unsigned int raw = acc32[(nl * ACCS2 + slot) * 2 + half];
            int qsum = (int)(raw - (unsigned int)qcnt[node] * QBIAS_U);
            float di = dis[node] * INV_QSCALE;
            out[(size_t)node * OUT_CH + lane] = (float)qsum * di + bc;
        }
    }
}

extern "C" void kernel_launch(void* const* d_in, const int* in_sizes, int n_in,
                              void* d_out, int out_size, void* d_ws, size_t ws_size,
                              hipStream_t stream) {
    const float* x  = (const float*)d_in[0];
    const int*   ei = (const int*)d_in[1];
    const float* ew = (const float*)d_in[2];
    const float* W  = (const float*)d_in[3];
    const float* b  = (const float*)d_in[4];
    float* out = (float*)d_out;

    // Workspace layout (4-byte units)
    unsigned int* hs = (unsigned int*)d_ws;                   // N*32 uints (12.8 MB)
    unsigned int* Wb = hs + (size_t)N_NODES * 32;             // 4096 uints
    int* lscan2d = (int*)(Wb + 4096);                         // NB1*LSTRIDE ints (1.2 MB)
    int* mtot    = lscan2d + (size_t)NB1 * LSTRIDE;           // NBINS (pad 800)
    float* dis   = (float*)(mtot + 800);                      // N floats
    int* qcnt    = (int*)(dis + N_NODES);                     // N ints
    int* brec2   = qcnt + N_NODES;                            // NBINS*RECCAP ints (6.4 MB)
    int2* brec   = (int2*)(brec2 + (size_t)NBINS * RECCAP);   // NB1*CH1 int2 (10 MB)
    (void)ws_size; (void)in_sizes; (void)n_in; (void)out_size;

    init_kernel<<<4, 256, 0, stream>>>(W, Wb);
    fused_kernel<<<NB1 + GEMM_BLOCKS, 512, 0, stream>>>(x, Wb, ei, ew,
                                                        lscan2d, brec, hs);
    binprep_kernel<<<NBINS, BPT, 0, stream>>>(lscan2d, brec, brec2, dis, qcnt, mtot);
    gather_kernel<<<NBINS, 512, 0, stream>>>(mtot, brec2, (const uint4*)hs,
                                             dis, qcnt, b, out);
}

// Round 6
// 159.227 us; speedup vs baseline: 1.1181x; 1.0032x over previous
//
#include <hip/hip_runtime.h>

#define N_NODES 100000
#define N_EDGES 1250000
#define IN_CH 128
#define OUT_CH 64

#define NPB 128           // nodes per bin; bin = row >> 7
#define ACCS2 33          // u64 acc row stride (pad): 128*33*8 = 33792 B LDS
#define NBINS 782         // ceil(100000/128)
#define LSTRIDE 783       // lscan2d row stride (NBINS+1 entries per sort block)
#define RECCAP 2048       // bin arena cap (mean 1598, sigma ~40, +11 sigma)
#define NB1 384           // sort blocks (srec 26KB -> 4 blocks/CU)
#define B1T 512
#define CH1 ((N_EDGES + NB1 - 1) / NB1)   // 3256 edges per sort block
#define MAXU ((CH1 + B1T - 1) / B1T)      // 7 edges cached per thread
#define GEMM_BLOCKS ((N_NODES + 127) / 128)  // 782 gemm blocks @ 128 nodes

// fixed-point: q = rn(val * sc), biased by 2^23 per contribution (sign-safe,
// ulp(2^23)=1.0; lo-half total stays << 2^32 at max ~45 edges/row)
#define QSCALE 8192.0f
#define QBIAS_F 8388608.0f
#define QBIAS_U 8388608u
#define INV_QSCALE 1.220703125e-4f   // 2^-13
#define SCALE_DEG 33554432.0f        // 2^25 fixed-point for degree accum
#define INV_SCALE_DEG 2.9802322387695312e-08f

typedef __attribute__((ext_vector_type(8))) short short8;
typedef __attribute__((ext_vector_type(4))) float f32x4;

// round-to-nearest-even f32 -> bf16
__device__ inline unsigned int f2bf(float f) {
    unsigned int u = __float_as_uint(f);
    unsigned int r = ((u >> 16) & 1u) + 0x7FFFu;
    return (u + r) >> 16;
}
__device__ inline float bf_lo(unsigned int p) { return __uint_as_float(p << 16); }
__device__ inline float bf_hi(unsigned int p) { return __uint_as_float(p & 0xFFFF0000u); }

// biased fixed-point quantize of one packed bf16x2, scaled by sc = QSCALE*dis_col
__device__ inline unsigned long long qpacks(unsigned int p, float sc) {
    unsigned int lo = (unsigned int)__float2int_rn(fmaf(bf_lo(p), sc, QBIAS_F));
    unsigned int hi = (unsigned int)__float2int_rn(fmaf(bf_hi(p), sc, QBIAS_F));
    return ((unsigned long long)hi << 32) | (unsigned long long)lo;
}

// ---------------------------------------------------------------------------
// Dispatch 1: blocks [0,NB1) = LDS counting sort of this block's edge chunk
// by bin (row>>7); ALL global writes coalesced (R0-R3 lesson: scattered 8B
// brec stores were a ~25us structural tail). Blocks [NB1,NB1+2) = W -> Wb
// bf16 MFMA-fragment conversion (init fused in; kills one launch).
// ---------------------------------------------------------------------------
__global__ __launch_bounds__(B1T) void sort_kernel(const int* __restrict__ ei,
                                                   const float* __restrict__ ew,
                                                   const float* __restrict__ W,
                                                   unsigned int* __restrict__ Wb,
                                                   int* __restrict__ lscan2d,
                                                   int2* __restrict__ brec) {
    __shared__ int2 srec[CH1];        // 26048 B sorted run
    __shared__ int shist[NBINS];      // hist, then reused as rank counters
    __shared__ int sscan[NBINS + 2];  // exclusive scan (incl. total at [NBINS])
    __shared__ int ssum[256];         // chunk sums for scan
    const int tid = threadIdx.x;

    if (blockIdx.x >= NB1) {
        int g = (blockIdx.x - NB1) * B1T + tid;   // 1024 lane-slots
        if (g < 1024) {
            int c = g >> 8;
            int t4 = (g >> 6) & 3;
            int l = g & 63;
            int q = l >> 4, r15 = l & 15;
            unsigned int o[4];
#pragma unroll
            for (int jj = 0; jj < 4; ++jj) {
                float f0 = W[(c * 32 + q * 8 + 2 * jj)     * OUT_CH + t4 * 16 + r15];
                float f1 = W[(c * 32 + q * 8 + 2 * jj + 1) * OUT_CH + t4 * 16 + r15];
                o[jj] = f2bf(f0) | (f2bf(f1) << 16);
            }
            *(uint4*)(Wb + (size_t)g * 4) = make_uint4(o[0], o[1], o[2], o[3]);
        }
        return;
    }

    // ----- sort -----
    for (int i = tid; i < NBINS; i += B1T) shist[i] = 0;
    __syncthreads();

    const int e0 = blockIdx.x * CH1;
    const int total = (e0 + CH1 < N_EDGES) ? CH1 : N_EDGES - e0;

    int rowv[MAXU], colv[MAXU];
    float wv[MAXU];
#pragma unroll
    for (int u = 0; u < MAXU; ++u) {
        int e = e0 + tid + u * B1T;
        bool ok = (tid + u * B1T) < total;
        rowv[u] = ok ? ei[e] : -1;
        colv[u] = ok ? ei[N_EDGES + e] : 0;
        wv[u]   = ok ? ew[e] : 0.0f;
        if (ok) atomicAdd(&shist[rowv[u] >> 7], 1);
    }
    __syncthreads();

    // block-local exclusive scan: shist[0..NBINS) -> sscan[0..NBINS]
    int a0 = 0, a1 = 0, a2 = 0, a3 = 0, part = 0;
    const int b0 = tid * 4;
    if (tid < 256) {
        a0 = (b0 + 0 < NBINS) ? shist[b0 + 0] : 0;
        a1 = (b0 + 1 < NBINS) ? shist[b0 + 1] : 0;
        a2 = (b0 + 2 < NBINS) ? shist[b0 + 2] : 0;
        a3 = (b0 + 3 < NBINS) ? shist[b0 + 3] : 0;
        part = a0 + a1 + a2 + a3;
        ssum[tid] = part;
    }
    __syncthreads();
#pragma unroll
    for (int d = 1; d < 256; d <<= 1) {
        int add = 0;
        if (tid >= d && tid < 256) add = ssum[tid - d];
        __syncthreads();
        if (tid < 256) ssum[tid] += add;
        __syncthreads();
    }
    if (tid < 256) {
        int base = ssum[tid] - part;   // exclusive chunk base
        if (b0 + 0 <= NBINS) sscan[b0 + 0] = base;
        if (b0 + 1 <= NBINS) sscan[b0 + 1] = base + a0;
        if (b0 + 2 <= NBINS) sscan[b0 + 2] = base + a0 + a1;
        if (b0 + 3 <= NBINS) sscan[b0 + 3] = base + a0 + a1 + a2;
    }
    __syncthreads();

    // reuse shist as rank counters
    for (int i = tid; i < NBINS; i += B1T) shist[i] = 0;
    __syncthreads();

    // scatter registers -> LDS sorted buffer (exact slots, memory-safe by
    // construction: sscan[bb]+rk < total <= CH1)
#pragma unroll
    for (int u = 0; u < MAXU; ++u) {
        if (rowv[u] >= 0) {
            int bb = rowv[u] >> 7;
            int rk = atomicAdd(&shist[bb], 1);
            srec[sscan[bb] + rk] = make_int2(((rowv[u] & 127) << 17) | colv[u],
                                             __float_as_int(wv[u]));
        }
    }
    __syncthreads();

    // coalesced streaming writeout
    for (int i = tid; i < total; i += B1T) brec[e0 + i] = srec[i];
    int* lrow = lscan2d + blockIdx.x * LSTRIDE;
    for (int i = tid; i <= NBINS; i += B1T) lrow[i] = sscan[i];
}

// ---------------------------------------------------------------------------
// Dispatch 2 (heterogeneous):
//   blocks [0, NBINS)   : binprep — concatenate this bin's NB1 sorted segments
//                         into a bin-contiguous 4B record arena via
//                         load-balanced binary-search copy; fused degree pass
//                         (ONE packed u64 LDS atomic per record: lo = wdeg
//                         fixed-point, hi = count). Emits brec2, dis, qcnt,
//                         mtot. Latency-bound -> hides under the GEMM blocks.
//   blocks [NBINS, +782): bf16-MFMA GEMM hs = bf16(x @ W), UNSCALED.
// (R5 post-mortem: binprep ran serial at ~14 us; GEMM is its natural
// overlap partner, not the sort.)
// ---------------------------------------------------------------------------
__global__ __launch_bounds__(512) void prep_gemm_kernel(const float* __restrict__ x,
                                                        const unsigned int* __restrict__ Wb,
                                                        const int* __restrict__ lscan2d,
                                                        const int2* __restrict__ brec,
                                                        int* __restrict__ brec2,
                                                        float* __restrict__ dis,
                                                        int* __restrict__ qcnt,
                                                        int* __restrict__ mtot,
                                                        unsigned int* __restrict__ hs) {
    __shared__ int sst[NB1];
    __shared__ int segoff[NB1];       // inclusive scan of segment lengths
    __shared__ int recs[RECCAP];      // 8192 B compacted 4B records
    __shared__ unsigned long long degcnt[NPB];  // lo: fixed-point wdeg, hi: count
    const int tid = threadIdx.x;

    if (blockIdx.x < NBINS) {
        // ----- binprep -----
        const int b = blockIdx.x;
        if (tid < NPB) degcnt[tid] = 0ull;
        if (tid < NB1) {
            int st = lscan2d[tid * LSTRIDE + b];
            int en = lscan2d[tid * LSTRIDE + b + 1];
            sst[tid] = st;
            segoff[tid] = en - st;
        }
        __syncthreads();
#pragma unroll
        for (int d = 1; d < NB1; d <<= 1) {   // Hillis-Steele inclusive scan
            int add = 0;
            if (tid >= d && tid < NB1) add = segoff[tid - d];
            __syncthreads();
            if (tid < NB1) segoff[tid] += add;
            __syncthreads();
        }
        const int m = segoff[NB1 - 1];

        for (int p = tid; p < m; p += 512) {
            // smallest k with segoff[k] > p
            int lo = 0, hi = NB1 - 1;
            while (lo < hi) {
                int mid = (lo + hi) >> 1;
                if (segoff[mid] > p) hi = mid; else lo = mid + 1;
            }
            int excl = (lo == 0) ? 0 : segoff[lo - 1];
            int2 rec = brec[(size_t)lo * CH1 + sst[lo] + (p - excl)];
            if (p < RECCAP) recs[p] = rec.x;
            unsigned int qd = (unsigned int)__float2int_rn(__int_as_float(rec.y) * SCALE_DEG);
            atomicAdd(&degcnt[rec.x >> 17], (1ull << 32) | (unsigned long long)qd);
        }
        __syncthreads();

        if (tid < NPB) {
            int node = b * NPB + tid;
            if (node < N_NODES) {
                unsigned long long dc = degcnt[tid];
                float d = (float)(unsigned int)dc * INV_SCALE_DEG;
                dis[node]  = (d == 0.0f) ? 0.0f : (1.0f / sqrtf(d));
                qcnt[node] = (int)(dc >> 32);
            }
        }
        int mc = (m < RECCAP) ? m : RECCAP;
        if (tid == 0) mtot[b] = mc;
        for (int p = tid; p < mc; p += 512)   // coalesced streaming writeout
            brec2[(size_t)b * RECCAP + p] = recs[p];
    } else {
        // ----- GEMM: 128 nodes per block, 8 waves x 16 rows -----
        const int blk  = blockIdx.x - NBINS;
        const int w    = tid >> 6;
        const int lane = tid & 63;
        const int q    = lane >> 4, r15 = lane & 15;
        const int node = blk * 128 + w * 16 + r15;
        const int nl   = (node < N_NODES) ? node : N_NODES - 1;   // clamp loads
        const float* xrow = x + (size_t)nl * IN_CH;

        f32x4 acc[4];
#pragma unroll
        for (int t = 0; t < 4; ++t) acc[t] = (f32x4){0.f, 0.f, 0.f, 0.f};

#pragma unroll
        for (int c = 0; c < 4; ++c) {
            float4 xa = *(const float4*)(xrow + c * 32 + q * 8);
            float4 xb = *(const float4*)(xrow + c * 32 + q * 8 + 4);
            short8 bfrag;
            bfrag[0] = (short)f2bf(xa.x); bfrag[1] = (short)f2bf(xa.y);
            bfrag[2] = (short)f2bf(xa.z); bfrag[3] = (short)f2bf(xa.w);
            bfrag[4] = (short)f2bf(xb.x); bfrag[5] = (short)f2bf(xb.y);
            bfrag[6] = (short)f2bf(xb.z); bfrag[7] = (short)f2bf(xb.w);
#pragma unroll
            for (int t = 0; t < 4; ++t) {
                short8 afrag = *(const short8*)(Wb + (size_t)((c * 4 + t) * 64 + lane) * 4);
                acc[t] = __builtin_amdgcn_mfma_f32_16x16x32_bf16(afrag, bfrag, acc[t], 0, 0, 0);
            }
        }

        if (node < N_NODES) {
#pragma unroll
            for (int t = 0; t < 4; ++t) {
                unsigned int p0 = f2bf(acc[t][0]) | (f2bf(acc[t][1]) << 16);
                unsigned int p1 = f2bf(acc[t][2]) | (f2bf(acc[t][3]) << 16);
                *(uint2*)(hs + (size_t)node * 32 + t * 8 + q * 2) = make_uint2(p0, p1);
            }
        }
    }
}

// ---------------------------------------------------------------------------
// Bin-gather: one 512-thread block per 128-node bin. Lean (R4 lesson: no
// preamble, LDS 33.8 KB -> 4 blocks/CU). 4B bin-contiguous records;
// u64-packed LDS atomics (2 biased fixed-point channels per ds_add_u64);
// 4-deep edge pipeline against the L3-latency-bound hs gather.
// ---------------------------------------------------------------------------
__global__ __launch_bounds__(512) void gather_kernel(const int* __restrict__ mtot,
                                                     const int* __restrict__ brec2,
                                                     const uint4* __restrict__ hs, // 8/row
                                                     const float* __restrict__ dis,
                                                     const int* __restrict__ qcnt,
                                                     const float* __restrict__ b,
                                                     float* __restrict__ out) {
    __shared__ unsigned long long acc[NPB * ACCS2];   // 33792 B
    const int tid = threadIdx.x;
    const int blk = blockIdx.x;
    for (int k = tid; k < NPB * ACCS2; k += 512) acc[k] = 0ull;
    __syncthreads();

    const int m = mtot[blk];
    const int rbase = blk * RECCAP;

    const int wid = tid >> 6, lane = tid & 63;
    const int sub = lane >> 3, l8 = lane & 7;

    for (int j0 = wid * 32; j0 < m; j0 += 256) {
        bool ok[4];
        int rec[4];
        uint4 p[4];
        float sc[4];
#pragma unroll
        for (int s = 0; s < 4; ++s) {
            int jj = j0 + 8 * s + sub;
            ok[s] = jj < m;
            rec[s] = ok[s] ? brec2[rbase + jj] : 0;
        }
#pragma unroll
        for (int s = 0; s < 4; ++s) {
            p[s] = ok[s] ? hs[(size_t)(rec[s] & 0x1FFFF) * 8 + l8]
                         : make_uint4(0, 0, 0, 0);
            sc[s] = ok[s] ? QSCALE * dis[rec[s] & 0x1FFFF] : 0.0f;
        }
#pragma unroll
        for (int s = 0; s < 4; ++s) {
            if (ok[s]) {
                int ba = (rec[s] >> 17) * ACCS2 + 4 * l8;
                atomicAdd(&acc[ba + 0], qpacks(p[s].x, sc[s]));
                atomicAdd(&acc[ba + 1], qpacks(p[s].y, sc[s]));
                atomicAdd(&acc[ba + 2], qpacks(p[s].z, sc[s]));
                atomicAdd(&acc[ba + 3], qpacks(p[s].w, sc[s]));
            }
        }
    }
    __syncthreads();

    // writeout: wave w handles node-locals [w*16, w*16+16); lane = channel c.
    // channel c lives in 32-bit half (c&1) of u64 slot (c>>1). Bias removal
    // uses the precomputed per-node edge count qcnt (binprep).
    const unsigned int* acc32 = (const unsigned int*)acc;
    float bc = b[lane];
    int half = lane & 1, slot = lane >> 1;
#pragma unroll 4
    for (int r = 0; r < 16; ++r) {
        int nl = wid * 16 + r;
        int node = blk * NPB + nl;
        if (node < N_NODES) {
            unsigned int raw = acc32[(nl * ACCS2 + slot) * 2 + half];
            int qsum = (int)(raw - (unsigned int)qcnt[node] * QBIAS_U);
            float di = dis[node] * INV_QSCALE;
            out[(size_t)node * OUT_CH + lane] = (float)qsum * di + bc;
        }
    }
}

extern "C" void kernel_launch(void* const* d_in, const int* in_sizes, int n_in,
                              void* d_out, int out_size, void* d_ws, size_t ws_size,
                              hipStream_t stream) {
    const float* x  = (const float*)d_in[0];
    const int*   ei = (const int*)d_in[1];
    const float* ew = (const float*)d_in[2];
    const float* W  = (const float*)d_in[3];
    const float* b  = (const float*)d_in[4];
    float* out = (float*)d_out;

    // Workspace layout (4-byte units)
    unsigned int* hs = (unsigned int*)d_ws;                   // N*32 uints (12.8 MB)
    unsigned int* Wb = hs + (size_t)N_NODES * 32;             // 4096 uints
    int* lscan2d = (int*)(Wb + 4096);                         // NB1*LSTRIDE ints (1.2 MB)
    int* mtot    = lscan2d + (size_t)NB1 * LSTRIDE;           // NBINS (pad 800)
    float* dis   = (float*)(mtot + 800);                      // N floats
    int* qcnt    = (int*)(dis + N_NODES);                     // N ints
    int* brec2   = qcnt + N_NODES;                            // NBINS*RECCAP ints (6.4 MB)
    int2* brec   = (int2*)(brec2 + (size_t)NBINS * RECCAP);   // NB1*CH1 int2 (10 MB)
    (void)ws_size; (void)in_sizes; (void)n_in; (void)out_size;

    sort_kernel<<<NB1 + 2, B1T, 0, stream>>>(ei, ew, W, Wb, lscan2d, brec);
    prep_gemm_kernel<<<NBINS + GEMM_BLOCKS, 512, 0, stream>>>(x, Wb, lscan2d, brec,
                                                              brec2, dis, qcnt,
                                                              mtot, hs);
    gather_kernel<<<NBINS, 512, 0, stream>>>(mtot, brec2, (const uint4*)hs,
                                             dis, qcnt, b, out);
}